// Round 1
// baseline (610.452 us; speedup 1.0000x reference)
//
#include <hip/hip_runtime.h>
#include <hip/hip_bf16.h>
#include <math.h>

#define D_   1024
#define H_   16
#define HD_  64
#define S_   2048
#define B_   2
#define FF_  4096
#define M_   (B_*S_)      // 4096 rows
#define QKVN (3*D_)       // 3072

typedef __bf16 bf16;
typedef bf16 bf16x8 __attribute__((ext_vector_type(8)));
typedef bf16 bf16x4 __attribute__((ext_vector_type(4)));
typedef float f32x4 __attribute__((ext_vector_type(4)));

#define MFMA16(a,b,c) __builtin_amdgcn_mfma_f32_16x16x32_bf16(a,b,c,0,0,0)

// ---------------- weight transpose + cast: W[K][N] f32 -> WT[N][K] bf16 ----------------
__global__ __launch_bounds__(256) void transpose_cast(const float* __restrict__ W,
                                                      bf16* __restrict__ WT,
                                                      int K, int N) {
    __shared__ float t[64][65];
    int k0 = blockIdx.x * 64, n0 = blockIdx.y * 64;
    int tid = threadIdx.x;
    #pragma unroll
    for (int i = 0; i < 16; i++) {
        int e = tid + i * 256; int r = e >> 6, c = e & 63;
        t[r][c] = W[(size_t)(k0 + r) * N + n0 + c];
    }
    __syncthreads();
    #pragma unroll
    for (int i = 0; i < 16; i++) {
        int e = tid + i * 256; int r = e >> 6, c = e & 63;
        WT[(size_t)(n0 + r) * K + k0 + c] = (bf16)t[c][r];
    }
}

// ---------------- concat q,k,v biases into one [3072] buffer ----------------
__global__ void concat3(const float* __restrict__ a, const float* __restrict__ b,
                        const float* __restrict__ c, float* __restrict__ o) {
    int i = blockIdx.x * 256 + threadIdx.x;
    o[i] = (i < 1024) ? a[i] : (i < 2048 ? b[i - 1024] : c[i - 2048]);
}

// ---------------- layernorm (ddof=1, eps on std) f32 in -> bf16 out ----------------
__global__ __launch_bounds__(256) void ln_kernel(const float* __restrict__ x,
                                                 const float* __restrict__ g,
                                                 const float* __restrict__ sh,
                                                 bf16* __restrict__ out) {
    int row = blockIdx.x * 4 + (threadIdx.x >> 6);
    int lane = threadIdx.x & 63;
    const float4* xr = (const float4*)(x + (size_t)row * D_);
    float4 v[4]; float sum = 0.f, ss = 0.f;
    #pragma unroll
    for (int c = 0; c < 4; c++) {
        v[c] = xr[lane + 64 * c];
        sum += v[c].x + v[c].y + v[c].z + v[c].w;
        ss  += v[c].x * v[c].x + v[c].y * v[c].y + v[c].z * v[c].z + v[c].w * v[c].w;
    }
    #pragma unroll
    for (int o = 32; o; o >>= 1) { sum += __shfl_xor(sum, o); ss += __shfl_xor(ss, o); }
    float mean = sum * (1.f / 1024.f);
    float var  = (ss - 1024.f * mean * mean) * (1.f / 1023.f);
    float inv  = 1.f / (sqrtf(var) + 1e-5f);
    const float4* gp = (const float4*)g;
    const float4* sp = (const float4*)sh;
    bf16x4* op = (bf16x4*)(out + (size_t)row * D_);
    #pragma unroll
    for (int c = 0; c < 4; c++) {
        int idx = lane + 64 * c;
        float4 gv = gp[idx], sv = sp[idx];
        float y0 = (v[c].x - mean) * inv * gv.x + sv.x;
        float y1 = (v[c].y - mean) * inv * gv.y + sv.y;
        float y2 = (v[c].z - mean) * inv * gv.z + sv.z;
        float y3 = (v[c].w - mean) * inv * gv.w + sv.w;
        op[idx] = (bf16x4){(bf16)y0, (bf16)y1, (bf16)y2, (bf16)y3};
    }
}

// ---------------- generic bf16 GEMM: C = A[M,K] @ BT[N,K]^T + bias (+epilogue) ----------------
// MODE 0: out bf16.  MODE 1: out f32, += res[M,N] f32.  MODE 2: GELU(exact), out bf16.
template<int MODE>
__global__ __launch_bounds__(256) void gemm_bt(const bf16* __restrict__ A,
                                               const bf16* __restrict__ BT,
                                               const float* __restrict__ bias,
                                               const float* __restrict__ res,
                                               void* __restrict__ outp,
                                               int M, int N, int K) {
    __shared__ __align__(16) bf16 a_lds[128 * 40];
    __shared__ __align__(16) bf16 b_lds[128 * 40];
    int tid = threadIdx.x;
    int m0 = blockIdx.y * 128, n0 = blockIdx.x * 128;
    int w = tid >> 6, lane = tid & 63;
    int wm = (w >> 1) * 64, wn = (w & 1) * 64;
    int lr = lane & 15, lh = lane >> 4;
    f32x4 acc[4][4] = {};
    for (int k0 = 0; k0 < K; k0 += 32) {
        #pragma unroll
        for (int i = 0; i < 2; i++) {
            int e = tid + i * 256; int r = e >> 2, cg = e & 3;
            *(bf16x8*)&a_lds[r * 40 + cg * 8] = *(const bf16x8*)&A[(size_t)(m0 + r) * K + k0 + cg * 8];
            *(bf16x8*)&b_lds[r * 40 + cg * 8] = *(const bf16x8*)&BT[(size_t)(n0 + r) * K + k0 + cg * 8];
        }
        __syncthreads();
        bf16x8 afr[4], bfr[4];
        #pragma unroll
        for (int i = 0; i < 4; i++) {
            afr[i] = *(const bf16x8*)&a_lds[(wm + i * 16 + lr) * 40 + lh * 8];
            bfr[i] = *(const bf16x8*)&b_lds[(wn + i * 16 + lr) * 40 + lh * 8];
        }
        #pragma unroll
        for (int i = 0; i < 4; i++)
            #pragma unroll
            for (int j = 0; j < 4; j++)
                acc[i][j] = MFMA16(afr[i], bfr[j], acc[i][j]);
        __syncthreads();
    }
    // epilogue
    #pragma unroll
    for (int i = 0; i < 4; i++) {
        #pragma unroll
        for (int j = 0; j < 4; j++) {
            int col = n0 + wn + j * 16 + lr;
            float bv = bias[col];
            #pragma unroll
            for (int r = 0; r < 4; r++) {
                int row = m0 + wm + i * 16 + lh * 4 + r;
                float vv = acc[i][j][r] + bv;
                if (MODE == 2) vv = 0.5f * vv * (1.f + erff(vv * 0.70710678118654752f));
                if (MODE == 1) vv += res[(size_t)row * N + col];
                if (MODE == 1) ((float*)outp)[(size_t)row * N + col] = vv;
                else           ((bf16*)outp)[(size_t)row * N + col] = (bf16)vv;
            }
        }
    }
}

// ---------------- causal flash attention ----------------
// grid: (S/64, B*H), 256 threads (4 waves x 16 q-rows). qkv: [B*S][3072] bf16 (q|k|v)
__global__ __launch_bounds__(256) void attn_kernel(const bf16* __restrict__ qkv,
                                                   bf16* __restrict__ ctx) {
    __shared__ __align__(16) bf16 k_lds[32 * 72];
    __shared__ __align__(16) bf16 vt_lds[64 * 40];
    __shared__ __align__(16) bf16 p_lds[4 * 16 * 40];
    int bh = blockIdx.y; int b = bh >> 4, h = bh & 15;
    int q0 = blockIdx.x * 64;
    int tid = threadIdx.x, w = tid >> 6, lane = tid & 63;
    int lr = lane & 15, lh = lane >> 4;
    const size_t RS = QKVN;  // row stride in elements
    const bf16* qbase = qkv + (size_t)b * S_ * RS + h * 64;
    const bf16* kbase = qbase + 1024;
    const bf16* vbase = qbase + 2048;

    int qrow = q0 + w * 16 + lr;
    bf16x8 aq[2];
    aq[0] = *(const bf16x8*)&qbase[(size_t)qrow * RS + lh * 8];
    aq[1] = *(const bf16x8*)&qbase[(size_t)qrow * RS + 32 + lh * 8];

    f32x4 o_acc[4] = {};
    float mrow[4], lrow[4];
    #pragma unroll
    for (int r = 0; r < 4; r++) { mrow[r] = -1e30f; lrow[r] = 0.f; }

    int ntile = q0 / 32 + 2;  // kv tiles with kv0 <= q0+63
    for (int t = 0; t < ntile; t++) {
        int kv0 = t * 32;
        {   // cooperative staging: K linear, V transposed
            int r = tid >> 3, cg = tid & 7;
            *(bf16x8*)&k_lds[r * 72 + cg * 8] =
                *(const bf16x8*)&kbase[(size_t)(kv0 + r) * RS + cg * 8];
            bf16x8 vv = *(const bf16x8*)&vbase[(size_t)(kv0 + r) * RS + cg * 8];
            #pragma unroll
            for (int i = 0; i < 8; i++) vt_lds[(cg * 8 + i) * 40 + r] = vv[i];
        }
        __syncthreads();

        // scores: 16x32 (2 C-frags), K over d=64 (2 chunks)
        f32x4 sc[2] = {};
        #pragma unroll
        for (int hf = 0; hf < 2; hf++)
            #pragma unroll
            for (int dc = 0; dc < 2; dc++) {
                bf16x8 bk = *(const bf16x8*)&k_lds[(hf * 16 + lr) * 72 + dc * 32 + lh * 8];
                sc[hf] = MFMA16(aq[dc], bk, sc[hf]);
            }

        // scale + causal mask, row max
        float pmax[4];
        #pragma unroll
        for (int r = 0; r < 4; r++) pmax[r] = -1e30f;
        #pragma unroll
        for (int hf = 0; hf < 2; hf++) {
            int kvg = kv0 + hf * 16 + lr;
            #pragma unroll
            for (int r = 0; r < 4; r++) {
                int qg = q0 + w * 16 + lh * 4 + r;
                float sv = sc[hf][r] * 0.125f;
                if (kvg > qg) sv = -100000.0f;
                sc[hf][r] = sv;
                pmax[r] = fmaxf(pmax[r], sv);
            }
        }
        #pragma unroll
        for (int o = 1; o < 16; o <<= 1)
            #pragma unroll
            for (int r = 0; r < 4; r++) pmax[r] = fmaxf(pmax[r], __shfl_xor(pmax[r], o));

        float scl[4], psum[4];
        #pragma unroll
        for (int r = 0; r < 4; r++) {
            float mn = fmaxf(mrow[r], pmax[r]);
            scl[r] = expf(mrow[r] - mn);
            mrow[r] = mn;
            psum[r] = 0.f;
        }
        #pragma unroll
        for (int hf = 0; hf < 2; hf++)
            #pragma unroll
            for (int r = 0; r < 4; r++) {
                float p = expf(sc[hf][r] - mrow[r]);
                sc[hf][r] = p;
                psum[r] += p;
            }
        #pragma unroll
        for (int o = 1; o < 16; o <<= 1)
            #pragma unroll
            for (int r = 0; r < 4; r++) psum[r] += __shfl_xor(psum[r], o);
        #pragma unroll
        for (int r = 0; r < 4; r++) lrow[r] = lrow[r] * scl[r] + psum[r];
        #pragma unroll
        for (int j = 0; j < 4; j++)
            #pragma unroll
            for (int r = 0; r < 4; r++) o_acc[j][r] *= scl[r];

        // P (C-layout) -> LDS -> A-layout fragments
        bf16* pw = &p_lds[w * 16 * 40];
        #pragma unroll
        for (int hf = 0; hf < 2; hf++)
            #pragma unroll
            for (int r = 0; r < 4; r++)
                pw[(lh * 4 + r) * 40 + hf * 16 + lr] = (bf16)sc[hf][r];
        asm volatile("s_waitcnt lgkmcnt(0)" ::: "memory");
        bf16x8 ap = *(const bf16x8*)&pw[lr * 40 + lh * 8];
        #pragma unroll
        for (int j = 0; j < 4; j++) {
            bf16x8 bv = *(const bf16x8*)&vt_lds[(j * 16 + lr) * 40 + lh * 8];
            o_acc[j] = MFMA16(ap, bv, o_acc[j]);
        }
        __syncthreads();
    }

    #pragma unroll
    for (int j = 0; j < 4; j++)
        #pragma unroll
        for (int r = 0; r < 4; r++) {
            int row = q0 + w * 16 + lh * 4 + r;
            int col = h * 64 + j * 16 + lr;
            ctx[((size_t)b * S_ + row) * D_ + col] = (bf16)(o_acc[j][r] / lrow[r]);
        }
}

extern "C" void kernel_launch(void* const* d_in, const int* in_sizes, int n_in,
                              void* d_out, int out_size, void* d_ws, size_t ws_size,
                              hipStream_t stream) {
    const float* x  = (const float*)d_in[0];
    const float* Wq = (const float*)d_in[1];
    const float* bq = (const float*)d_in[2];
    const float* Wk = (const float*)d_in[3];
    const float* bk = (const float*)d_in[4];
    const float* Wv = (const float*)d_in[5];
    const float* bv = (const float*)d_in[6];
    const float* Wo = (const float*)d_in[7];
    const float* bo = (const float*)d_in[8];
    const float* W1 = (const float*)d_in[9];
    const float* b1 = (const float*)d_in[10];
    const float* W2 = (const float*)d_in[11];
    const float* b2 = (const float*)d_in[12];
    const float* g1 = (const float*)d_in[13];
    const float* s1 = (const float*)d_in[14];
    const float* g2 = (const float*)d_in[15];
    const float* s2 = (const float*)d_in[16];
    float* out = (float*)d_out;

    char* ws = (char*)d_ws;
    size_t off = 0;
    auto alloc = [&](size_t bytes) -> char* {
        char* p = ws + off; off += (bytes + 255) & ~(size_t)255; return p;
    };
    bf16*  wt_qkv = (bf16*)alloc((size_t)QKVN * D_ * 2);
    bf16*  wt_o   = (bf16*)alloc((size_t)D_ * D_ * 2);
    bf16*  wt_1   = (bf16*)alloc((size_t)FF_ * D_ * 2);
    bf16*  wt_2   = (bf16*)alloc((size_t)D_ * FF_ * 2);
    float* qkvb   = (float*)alloc((size_t)QKVN * 4);
    bf16*  h1     = (bf16*)alloc((size_t)M_ * D_ * 2);
    bf16*  qkv    = (bf16*)alloc((size_t)M_ * QKVN * 2);
    bf16*  ctx    = (bf16*)alloc((size_t)M_ * D_ * 2);
    float* x2     = (float*)alloc((size_t)M_ * D_ * 4);
    bf16*  h2     = (bf16*)alloc((size_t)M_ * D_ * 2);
    bf16*  gbuf   = (bf16*)alloc((size_t)M_ * FF_ * 2);

    // weight prep
    transpose_cast<<<dim3(16, 16), 256, 0, stream>>>(Wq, wt_qkv, D_, D_);
    transpose_cast<<<dim3(16, 16), 256, 0, stream>>>(Wk, wt_qkv + (size_t)D_ * D_, D_, D_);
    transpose_cast<<<dim3(16, 16), 256, 0, stream>>>(Wv, wt_qkv + (size_t)2 * D_ * D_, D_, D_);
    transpose_cast<<<dim3(16, 16), 256, 0, stream>>>(Wo, wt_o, D_, D_);
    transpose_cast<<<dim3(16, 64), 256, 0, stream>>>(W1, wt_1, D_, FF_);
    transpose_cast<<<dim3(64, 16), 256, 0, stream>>>(W2, wt_2, FF_, D_);
    concat3<<<12, 256, 0, stream>>>(bq, bk, bv, qkvb);

    // block
    ln_kernel<<<M_ / 4, 256, 0, stream>>>(x, g1, s1, h1);
    gemm_bt<0><<<dim3(QKVN / 128, M_ / 128), 256, 0, stream>>>(h1, wt_qkv, qkvb, nullptr, qkv, M_, QKVN, D_);
    attn_kernel<<<dim3(S_ / 64, B_ * H_), 256, 0, stream>>>(qkv, ctx);
    gemm_bt<1><<<dim3(D_ / 128, M_ / 128), 256, 0, stream>>>(ctx, wt_o, bo, x, x2, M_, D_, D_);
    ln_kernel<<<M_ / 4, 256, 0, stream>>>(x2, g2, s2, h2);
    gemm_bt<2><<<dim3(FF_ / 128, M_ / 128), 256, 0, stream>>>(h2, wt_1, b1, nullptr, gbuf, M_, FF_, D_);
    gemm_bt<1><<<dim3(D_ / 128, M_ / 128), 256, 0, stream>>>(gbuf, wt_2, b2, x2, out, M_, D_, FF_);
}

// Round 2
// 459.206 us; speedup vs baseline: 1.3294x; 1.3294x over previous
//
#include <hip/hip_runtime.h>
#include <hip/hip_bf16.h>
#include <math.h>

#define D_   1024
#define H_   16
#define HD_  64
#define S_   2048
#define B_   2
#define FF_  4096
#define M_   (B_*S_)      // 4096 rows
#define QKVN (3*D_)       // 3072

typedef __bf16 bf16;
typedef bf16 bf16x8 __attribute__((ext_vector_type(8)));
typedef bf16 bf16x4 __attribute__((ext_vector_type(4)));
typedef float f32x4 __attribute__((ext_vector_type(4)));

#define MFMA16(a,b,c) __builtin_amdgcn_mfma_f32_16x16x32_bf16(a,b,c,0,0,0)

// async global->LDS 16B per lane (wave-uniform LDS base + lane*16)
__device__ __forceinline__ void gld16(const void* g, void* l) {
    __builtin_amdgcn_global_load_lds(
        (const __attribute__((address_space(1))) void*)g,
        (__attribute__((address_space(3))) void*)l, 16, 0, 0);
}

// ---------------- weight transpose + cast: W[K][N] f32 -> WT[N][K] bf16 ----------------
__global__ __launch_bounds__(256) void transpose_cast(const float* __restrict__ W,
                                                      bf16* __restrict__ WT,
                                                      int K, int N) {
    __shared__ float t[64][65];
    int k0 = blockIdx.x * 64, n0 = blockIdx.y * 64;
    int tid = threadIdx.x;
    #pragma unroll
    for (int i = 0; i < 16; i++) {
        int e = tid + i * 256; int r = e >> 6, c = e & 63;
        t[r][c] = W[(size_t)(k0 + r) * N + n0 + c];
    }
    __syncthreads();
    #pragma unroll
    for (int i = 0; i < 16; i++) {
        int e = tid + i * 256; int r = e >> 6, c = e & 63;
        WT[(size_t)(n0 + r) * K + k0 + c] = (bf16)t[c][r];
    }
}

// ---------------- transpose V section of qkv into VT[bh][d][s] ----------------
__global__ __launch_bounds__(256) void transpose_v(const bf16* __restrict__ qkv,
                                                   bf16* __restrict__ VT) {
    __shared__ __align__(16) bf16 t[64][72];
    int bh = blockIdx.y; int b = bh >> 4, h = bh & 15;
    int s0 = blockIdx.x * 64;
    const bf16* vbase = qkv + (size_t)b * S_ * QKVN + 2048 + h * 64;
    int tid = threadIdx.x;
    #pragma unroll
    for (int i = 0; i < 2; i++) {
        int e = tid + i * 256; int r = e >> 3, cg = e & 7;
        *(bf16x8*)&t[r][cg * 8] = *(const bf16x8*)&vbase[(size_t)(s0 + r) * QKVN + cg * 8];
    }
    __syncthreads();
    #pragma unroll
    for (int i = 0; i < 2; i++) {
        int e = tid + i * 256; int d = e >> 3, cg = e & 7;
        bf16x8 v;
        #pragma unroll
        for (int j = 0; j < 8; j++) v[j] = t[cg * 8 + j][d];
        *(bf16x8*)&VT[((size_t)bh * 64 + d) * S_ + s0 + cg * 8] = v;
    }
}

// ---------------- concat q,k,v biases into one [3072] buffer ----------------
__global__ void concat3(const float* __restrict__ a, const float* __restrict__ b,
                        const float* __restrict__ c, float* __restrict__ o) {
    int i = blockIdx.x * 256 + threadIdx.x;
    o[i] = (i < 1024) ? a[i] : (i < 2048 ? b[i - 1024] : c[i - 2048]);
}

// ---------------- layernorm (ddof=1, eps on std) f32 in -> bf16 out ----------------
__global__ __launch_bounds__(256) void ln_kernel(const float* __restrict__ x,
                                                 const float* __restrict__ g,
                                                 const float* __restrict__ sh,
                                                 bf16* __restrict__ out) {
    int row = blockIdx.x * 4 + (threadIdx.x >> 6);
    int lane = threadIdx.x & 63;
    const float4* xr = (const float4*)(x + (size_t)row * D_);
    float4 v[4]; float sum = 0.f, ss = 0.f;
    #pragma unroll
    for (int c = 0; c < 4; c++) {
        v[c] = xr[lane + 64 * c];
        sum += v[c].x + v[c].y + v[c].z + v[c].w;
        ss  += v[c].x * v[c].x + v[c].y * v[c].y + v[c].z * v[c].z + v[c].w * v[c].w;
    }
    #pragma unroll
    for (int o = 32; o; o >>= 1) { sum += __shfl_xor(sum, o); ss += __shfl_xor(ss, o); }
    float mean = sum * (1.f / 1024.f);
    float var  = (ss - 1024.f * mean * mean) * (1.f / 1023.f);
    float inv  = 1.f / (sqrtf(var) + 1e-5f);
    const float4* gp = (const float4*)g;
    const float4* sp = (const float4*)sh;
    bf16x4* op = (bf16x4*)(out + (size_t)row * D_);
    #pragma unroll
    for (int c = 0; c < 4; c++) {
        int idx = lane + 64 * c;
        float4 gv = gp[idx], sv = sp[idx];
        float y0 = (v[c].x - mean) * inv * gv.x + sv.x;
        float y1 = (v[c].y - mean) * inv * gv.y + sv.y;
        float y2 = (v[c].z - mean) * inv * gv.z + sv.z;
        float y3 = (v[c].w - mean) * inv * gv.w + sv.w;
        op[idx] = (bf16x4){(bf16)y0, (bf16)y1, (bf16)y2, (bf16)y3};
    }
}

// ---------------- m97-structure bf16 GEMM: C = A[M,K] @ BT[N,K]^T + bias (+epilogue) ----------------
// MODE 0: out bf16.  MODE 1: out f32, += res[M,N] f32.  MODE 2: GELU(exact), out bf16.
template<int MODE>
__global__ __launch_bounds__(256) void gemm_bt(const bf16* __restrict__ A,
                                               const bf16* __restrict__ BT,
                                               const float* __restrict__ bias,
                                               const float* __restrict__ res,
                                               void* __restrict__ outp,
                                               int M, int N, int K) {
    __shared__ __align__(16) bf16 a_lds[128 * 32];
    __shared__ __align__(16) bf16 b_lds[128 * 32];
    int tid = threadIdx.x;
    int m0 = blockIdx.y * 128, n0 = blockIdx.x * 128;
    int w = tid >> 6, lane = tid & 63;
    int wm = (w >> 1) * 64, wn = (w & 1) * 64;
    int lr = lane & 15, lh = lane >> 4;
    // staging granules: gi = w*128 + s*64 + lane; row = gi>>2, col-granule = gi&3
    int gi0 = w * 128 + lane;
    int r0 = gi0 >> 2, c0 = gi0 & 3;
    int gi1 = gi0 + 64;
    int r1 = gi1 >> 2, c1 = gi1 & 3;
    f32x4 acc[4][4] = {};
    for (int k0 = 0; k0 < K; k0 += 32) {
        gld16(&A [(size_t)(m0 + r0) * K + k0 + c0 * 8], &a_lds[(w * 128)      * 8]);
        gld16(&A [(size_t)(m0 + r1) * K + k0 + c1 * 8], &a_lds[(w * 128 + 64) * 8]);
        gld16(&BT[(size_t)(n0 + r0) * K + k0 + c0 * 8], &b_lds[(w * 128)      * 8]);
        gld16(&BT[(size_t)(n0 + r1) * K + k0 + c1 * 8], &b_lds[(w * 128 + 64) * 8]);
        __syncthreads();
        bf16x8 afr[4], bfr[4];
        #pragma unroll
        for (int i = 0; i < 4; i++) {
            afr[i] = *(const bf16x8*)&a_lds[(wm + i * 16 + lr) * 32 + lh * 8];
            bfr[i] = *(const bf16x8*)&b_lds[(wn + i * 16 + lr) * 32 + lh * 8];
        }
        #pragma unroll
        for (int i = 0; i < 4; i++)
            #pragma unroll
            for (int j = 0; j < 4; j++)
                acc[i][j] = MFMA16(afr[i], bfr[j], acc[i][j]);
        __syncthreads();
    }
    // epilogue
    #pragma unroll
    for (int i = 0; i < 4; i++) {
        #pragma unroll
        for (int j = 0; j < 4; j++) {
            int col = n0 + wn + j * 16 + lr;
            float bv = bias[col];
            #pragma unroll
            for (int r = 0; r < 4; r++) {
                int row = m0 + wm + i * 16 + lh * 4 + r;
                float vv = acc[i][j][r] + bv;
                if (MODE == 2) vv = 0.5f * vv * (1.f + erff(vv * 0.70710678118654752f));
                if (MODE == 1) vv += res[(size_t)row * N + col];
                if (MODE == 1) ((float*)outp)[(size_t)row * N + col] = vv;
                else           ((bf16*)outp)[(size_t)row * N + col] = (bf16)vv;
            }
        }
    }
}

// ---------------- causal flash attention v2 ----------------
// grid: (B*H, S/64) with q-tile reversed (heavy first); 256 threads = 4 waves x 16 q-rows.
// qkv: [B*S][3072] bf16 (q|k|v).  VT: [B*H][64][S] bf16 (pre-transposed V).
__global__ __launch_bounds__(256) void attn_kernel(const bf16* __restrict__ qkv,
                                                   const bf16* __restrict__ VT,
                                                   bf16* __restrict__ ctx) {
    __shared__ __align__(16) bf16 k_lds[64 * 72];
    __shared__ __align__(16) bf16 vt_lds[64 * 72];
    __shared__ __align__(16) bf16 p_lds[4 * 16 * 72];
    int bh = blockIdx.x; int b = bh >> 4, h = bh & 15;
    int qt = gridDim.y - 1 - blockIdx.y;
    int q0 = qt * 64;
    int tid = threadIdx.x, w = tid >> 6, lane = tid & 63;
    int lr = lane & 15, lh = lane >> 4;
    const size_t RS = QKVN;
    const bf16* qbase = qkv + (size_t)b * S_ * RS + h * 64;
    const bf16* kbase = qbase + 1024;
    const bf16* vtb = VT + (size_t)bh * 64 * S_;

    int qrow = q0 + w * 16 + lr;
    bf16x8 aq[2];
    aq[0] = *(const bf16x8*)&qbase[(size_t)qrow * RS + lh * 8];
    aq[1] = *(const bf16x8*)&qbase[(size_t)qrow * RS + 32 + lh * 8];

    f32x4 o_acc[4] = {};
    float mrow[4], lrow[4];
    #pragma unroll
    for (int r = 0; r < 4; r++) { mrow[r] = -1e30f; lrow[r] = 0.f; }

    int er = tid >> 3, ecg = tid & 7;       // staging split: 64 rows x 8 col-granules, 2 iters
    int ntile = qt + 1;
    for (int t = 0; t < ntile; t++) {
        int kv0 = t * 64;
        #pragma unroll
        for (int i = 0; i < 2; i++) {
            int r = er + i * 32;
            *(bf16x8*)&k_lds [r * 72 + ecg * 8] = *(const bf16x8*)&kbase[(size_t)(kv0 + r) * RS + ecg * 8];
            *(bf16x8*)&vt_lds[r * 72 + ecg * 8] = *(const bf16x8*)&vtb  [(size_t)r * S_ + kv0 + ecg * 8];
        }
        __syncthreads();

        // scores: 16 q x 64 kv (4 C-frags), K over d=64 (2 chunks)
        f32x4 sc[4] = {};
        #pragma unroll
        for (int kf = 0; kf < 4; kf++)
            #pragma unroll
            for (int dc = 0; dc < 2; dc++) {
                bf16x8 bk = *(const bf16x8*)&k_lds[(kf * 16 + lr) * 72 + dc * 32 + lh * 8];
                sc[kf] = MFMA16(aq[dc], bk, sc[kf]);
            }

        // scale + causal mask, row max
        float pmax[4];
        #pragma unroll
        for (int r = 0; r < 4; r++) pmax[r] = -1e30f;
        #pragma unroll
        for (int kf = 0; kf < 4; kf++) {
            int kvg = kv0 + kf * 16 + lr;
            #pragma unroll
            for (int r = 0; r < 4; r++) {
                int qg = q0 + w * 16 + lh * 4 + r;
                float sv = sc[kf][r] * 0.125f;
                if (kvg > qg) sv = -100000.0f;
                sc[kf][r] = sv;
                pmax[r] = fmaxf(pmax[r], sv);
            }
        }
        #pragma unroll
        for (int o = 1; o < 16; o <<= 1)
            #pragma unroll
            for (int r = 0; r < 4; r++) pmax[r] = fmaxf(pmax[r], __shfl_xor(pmax[r], o));

        float scl[4], psum[4];
        #pragma unroll
        for (int r = 0; r < 4; r++) {
            float mn = fmaxf(mrow[r], pmax[r]);
            scl[r] = __expf(mrow[r] - mn);
            mrow[r] = mn;
            psum[r] = 0.f;
        }
        #pragma unroll
        for (int kf = 0; kf < 4; kf++)
            #pragma unroll
            for (int r = 0; r < 4; r++) {
                float p = __expf(sc[kf][r] - mrow[r]);
                sc[kf][r] = p;
                psum[r] += p;
            }
        #pragma unroll
        for (int o = 1; o < 16; o <<= 1)
            #pragma unroll
            for (int r = 0; r < 4; r++) psum[r] += __shfl_xor(psum[r], o);
        #pragma unroll
        for (int r = 0; r < 4; r++) lrow[r] = lrow[r] * scl[r] + psum[r];
        #pragma unroll
        for (int j = 0; j < 4; j++)
            #pragma unroll
            for (int r = 0; r < 4; r++) o_acc[j][r] *= scl[r];

        // P (C-layout) -> per-wave LDS -> A-layout fragments
        bf16* pw = &p_lds[w * 16 * 72];
        #pragma unroll
        for (int kf = 0; kf < 4; kf++)
            #pragma unroll
            for (int r = 0; r < 4; r++)
                pw[(lh * 4 + r) * 72 + kf * 16 + lr] = (bf16)sc[kf][r];
        asm volatile("s_waitcnt lgkmcnt(0)" ::: "memory");
        __builtin_amdgcn_sched_barrier(0);
        bf16x8 ap[2];
        ap[0] = *(const bf16x8*)&pw[lr * 72 + lh * 8];
        ap[1] = *(const bf16x8*)&pw[lr * 72 + 32 + lh * 8];
        #pragma unroll
        for (int df = 0; df < 4; df++) {
            #pragma unroll
            for (int kc = 0; kc < 2; kc++) {
                bf16x8 bv = *(const bf16x8*)&vt_lds[(df * 16 + lr) * 72 + kc * 32 + lh * 8];
                o_acc[df] = MFMA16(ap[kc], bv, o_acc[df]);
            }
        }
        __syncthreads();
    }

    #pragma unroll
    for (int df = 0; df < 4; df++)
        #pragma unroll
        for (int r = 0; r < 4; r++) {
            int row = q0 + w * 16 + lh * 4 + r;
            int col = h * 64 + df * 16 + lr;
            ctx[((size_t)b * S_ + row) * D_ + col] = (bf16)(o_acc[df][r] / lrow[r]);
        }
}

extern "C" void kernel_launch(void* const* d_in, const int* in_sizes, int n_in,
                              void* d_out, int out_size, void* d_ws, size_t ws_size,
                              hipStream_t stream) {
    const float* x  = (const float*)d_in[0];
    const float* Wq = (const float*)d_in[1];
    const float* bq = (const float*)d_in[2];
    const float* Wk = (const float*)d_in[3];
    const float* bk = (const float*)d_in[4];
    const float* Wv = (const float*)d_in[5];
    const float* bv = (const float*)d_in[6];
    const float* Wo = (const float*)d_in[7];
    const float* bo = (const float*)d_in[8];
    const float* W1 = (const float*)d_in[9];
    const float* b1 = (const float*)d_in[10];
    const float* W2 = (const float*)d_in[11];
    const float* b2 = (const float*)d_in[12];
    const float* g1 = (const float*)d_in[13];
    const float* s1 = (const float*)d_in[14];
    const float* g2 = (const float*)d_in[15];
    const float* s2 = (const float*)d_in[16];
    float* out = (float*)d_out;

    char* ws = (char*)d_ws;
    size_t off = 0;
    auto alloc = [&](size_t bytes) -> char* {
        char* p = ws + off; off += (bytes + 255) & ~(size_t)255; return p;
    };
    bf16*  wt_qkv = (bf16*)alloc((size_t)QKVN * D_ * 2);
    bf16*  wt_o   = (bf16*)alloc((size_t)D_ * D_ * 2);
    bf16*  wt_1   = (bf16*)alloc((size_t)FF_ * D_ * 2);
    bf16*  wt_2   = (bf16*)alloc((size_t)D_ * FF_ * 2);
    float* qkvb   = (float*)alloc((size_t)QKVN * 4);
    bf16*  h1     = (bf16*)alloc((size_t)M_ * D_ * 2);
    bf16*  qkv    = (bf16*)alloc((size_t)M_ * QKVN * 2);
    bf16*  vtbuf  = (bf16*)alloc((size_t)M_ * D_ * 2);
    bf16*  ctx    = (bf16*)alloc((size_t)M_ * D_ * 2);
    float* x2     = (float*)alloc((size_t)M_ * D_ * 4);
    bf16*  h2     = (bf16*)alloc((size_t)M_ * D_ * 2);
    bf16*  gbuf   = (bf16*)alloc((size_t)M_ * FF_ * 2);

    // weight prep
    transpose_cast<<<dim3(16, 16), 256, 0, stream>>>(Wq, wt_qkv, D_, D_);
    transpose_cast<<<dim3(16, 16), 256, 0, stream>>>(Wk, wt_qkv + (size_t)D_ * D_, D_, D_);
    transpose_cast<<<dim3(16, 16), 256, 0, stream>>>(Wv, wt_qkv + (size_t)2 * D_ * D_, D_, D_);
    transpose_cast<<<dim3(16, 16), 256, 0, stream>>>(Wo, wt_o, D_, D_);
    transpose_cast<<<dim3(16, 64), 256, 0, stream>>>(W1, wt_1, D_, FF_);
    transpose_cast<<<dim3(64, 16), 256, 0, stream>>>(W2, wt_2, FF_, D_);
    concat3<<<12, 256, 0, stream>>>(bq, bk, bv, qkvb);

    // block
    ln_kernel<<<M_ / 4, 256, 0, stream>>>(x, g1, s1, h1);
    gemm_bt<0><<<dim3(QKVN / 128, M_ / 128), 256, 0, stream>>>(h1, wt_qkv, qkvb, nullptr, qkv, M_, QKVN, D_);
    transpose_v<<<dim3(S_ / 64, B_ * H_), 256, 0, stream>>>(qkv, vtbuf);
    attn_kernel<<<dim3(B_ * H_, S_ / 64), 256, 0, stream>>>(qkv, vtbuf, ctx);
    gemm_bt<1><<<dim3(D_ / 128, M_ / 128), 256, 0, stream>>>(ctx, wt_o, bo, x, x2, M_, D_, D_);
    ln_kernel<<<M_ / 4, 256, 0, stream>>>(x2, g2, s2, h2);
    gemm_bt<2><<<dim3(FF_ / 128, M_ / 128), 256, 0, stream>>>(h2, wt_1, b1, nullptr, gbuf, M_, FF_, D_);
    gemm_bt<1><<<dim3(D_ / 128, M_ / 128), 256, 0, stream>>>(gbuf, wt_2, b2, x2, out, M_, D_, FF_);
}

// Round 3
// 431.717 us; speedup vs baseline: 1.4140x; 1.0637x over previous
//
#include <hip/hip_runtime.h>
#include <hip/hip_bf16.h>
#include <math.h>

#define D_   1024
#define H_   16
#define HD_  64
#define S_   2048
#define B_   2
#define FF_  4096
#define M_   (B_*S_)      // 4096 rows
#define QKVN (3*D_)       // 3072

typedef __bf16 bf16;
typedef bf16 bf16x8 __attribute__((ext_vector_type(8)));
typedef bf16 bf16x4 __attribute__((ext_vector_type(4)));
typedef float f32x4 __attribute__((ext_vector_type(4)));

#define MFMA16(a,b,c) __builtin_amdgcn_mfma_f32_16x16x32_bf16(a,b,c,0,0,0)

// async global->LDS 16B per lane (wave-uniform LDS base + lane*16)
__device__ __forceinline__ void gld16(const void* g, void* l) {
    __builtin_amdgcn_global_load_lds(
        (const __attribute__((address_space(1))) void*)g,
        (__attribute__((address_space(3))) void*)l, 16, 0, 0);
}

// ---------------- weight transpose + cast: W[K][N] f32 -> WT[N][K] bf16 ----------------
__global__ __launch_bounds__(256) void transpose_cast(const float* __restrict__ W,
                                                      bf16* __restrict__ WT,
                                                      int K, int N) {
    __shared__ float t[64][65];
    int k0 = blockIdx.x * 64, n0 = blockIdx.y * 64;
    int tid = threadIdx.x;
    #pragma unroll
    for (int i = 0; i < 16; i++) {
        int e = tid + i * 256; int r = e >> 6, c = e & 63;
        t[r][c] = W[(size_t)(k0 + r) * N + n0 + c];
    }
    __syncthreads();
    #pragma unroll
    for (int i = 0; i < 16; i++) {
        int e = tid + i * 256; int r = e >> 6, c = e & 63;
        WT[(size_t)(n0 + r) * K + k0 + c] = (bf16)t[c][r];
    }
}

// ---------------- transpose V section of qkv into VT[bh][d][s] ----------------
__global__ __launch_bounds__(256) void transpose_v(const bf16* __restrict__ qkv,
                                                   bf16* __restrict__ VT) {
    __shared__ __align__(16) bf16 t[64][72];
    int bh = blockIdx.y; int b = bh >> 4, h = bh & 15;
    int s0 = blockIdx.x * 64;
    const bf16* vbase = qkv + (size_t)b * S_ * QKVN + 2048 + h * 64;
    int tid = threadIdx.x;
    #pragma unroll
    for (int i = 0; i < 2; i++) {
        int e = tid + i * 256; int r = e >> 3, cg = e & 7;
        *(bf16x8*)&t[r][cg * 8] = *(const bf16x8*)&vbase[(size_t)(s0 + r) * QKVN + cg * 8];
    }
    __syncthreads();
    #pragma unroll
    for (int i = 0; i < 2; i++) {
        int e = tid + i * 256; int d = e >> 3, cg = e & 7;
        bf16x8 v;
        #pragma unroll
        for (int j = 0; j < 8; j++) v[j] = t[cg * 8 + j][d];
        *(bf16x8*)&VT[((size_t)bh * 64 + d) * S_ + s0 + cg * 8] = v;
    }
}

// ---------------- concat q,k,v biases into one [3072] buffer ----------------
__global__ void concat3(const float* __restrict__ a, const float* __restrict__ b,
                        const float* __restrict__ c, float* __restrict__ o) {
    int i = blockIdx.x * 256 + threadIdx.x;
    o[i] = (i < 1024) ? a[i] : (i < 2048 ? b[i - 1024] : c[i - 2048]);
}

// ---------------- layernorm (ddof=1, eps on std) f32 in -> bf16 out ----------------
__global__ __launch_bounds__(256) void ln_kernel(const float* __restrict__ x,
                                                 const float* __restrict__ g,
                                                 const float* __restrict__ sh,
                                                 bf16* __restrict__ out) {
    int row = blockIdx.x * 4 + (threadIdx.x >> 6);
    int lane = threadIdx.x & 63;
    const float4* xr = (const float4*)(x + (size_t)row * D_);
    float4 v[4]; float sum = 0.f, ss = 0.f;
    #pragma unroll
    for (int c = 0; c < 4; c++) {
        v[c] = xr[lane + 64 * c];
        sum += v[c].x + v[c].y + v[c].z + v[c].w;
        ss  += v[c].x * v[c].x + v[c].y * v[c].y + v[c].z * v[c].z + v[c].w * v[c].w;
    }
    #pragma unroll
    for (int o = 32; o; o >>= 1) { sum += __shfl_xor(sum, o); ss += __shfl_xor(ss, o); }
    float mean = sum * (1.f / 1024.f);
    float var  = (ss - 1024.f * mean * mean) * (1.f / 1023.f);
    float inv  = 1.f / (sqrtf(var) + 1e-5f);
    const float4* gp = (const float4*)g;
    const float4* sp = (const float4*)sh;
    bf16x4* op = (bf16x4*)(out + (size_t)row * D_);
    #pragma unroll
    for (int c = 0; c < 4; c++) {
        int idx = lane + 64 * c;
        float4 gv = gp[idx], sv = sp[idx];
        float y0 = (v[c].x - mean) * inv * gv.x + sv.x;
        float y1 = (v[c].y - mean) * inv * gv.y + sv.y;
        float y2 = (v[c].z - mean) * inv * gv.z + sv.z;
        float y3 = (v[c].w - mean) * inv * gv.w + sv.w;
        op[idx] = (bf16x4){(bf16)y0, (bf16)y1, (bf16)y2, (bf16)y3};
    }
}

// ------- 2-phase double-buffered bf16 GEMM: C = A[M,K] @ BT[N,K]^T + bias (+epilogue) -------
// MODE 0: out bf16.  MODE 1: out f32, += res[M,N] f32.  MODE 2: GELU(exact), out bf16.
template<int MODE>
__global__ __launch_bounds__(256) void gemm_bt(const bf16* __restrict__ A,
                                               const bf16* __restrict__ BT,
                                               const float* __restrict__ bias,
                                               const float* __restrict__ res,
                                               void* __restrict__ outp,
                                               int M, int N, int K) {
    __shared__ __align__(16) bf16 a_lds[2][128 * 32];
    __shared__ __align__(16) bf16 b_lds[2][128 * 32];
    int tid = threadIdx.x;
    // XCD-chunked bijective swizzle (grids here are multiples of 8)
    int nbx = gridDim.x;
    int nwg = nbx * gridDim.y;
    int flat = blockIdx.y * nbx + blockIdx.x;
    int chunk = nwg >> 3;
    int swz = (flat & 7) * chunk + (flat >> 3);
    int m0 = (swz / nbx) * 128, n0 = (swz % nbx) * 128;
    int w = tid >> 6, lane = tid & 63;
    int wm = (w >> 1) * 64, wn = (w & 1) * 64;
    int lr = lane & 15, lh = lane >> 4;
    // staging granules: gi = w*128 + s*64 + lane; row = gi>>2, col-granule = gi&3
    int gi0 = w * 128 + lane;
    int r0 = gi0 >> 2, c0 = gi0 & 3;
    int gi1 = gi0 + 64;
    int r1 = gi1 >> 2, c1 = gi1 & 3;

    auto STAGE = [&](int buf, int k0) {
        gld16(&A [(size_t)(m0 + r0) * K + k0 + c0 * 8], &a_lds[buf][(w * 128)      * 8]);
        gld16(&A [(size_t)(m0 + r1) * K + k0 + c1 * 8], &a_lds[buf][(w * 128 + 64) * 8]);
        gld16(&BT[(size_t)(n0 + r0) * K + k0 + c0 * 8], &b_lds[buf][(w * 128)      * 8]);
        gld16(&BT[(size_t)(n0 + r1) * K + k0 + c1 * 8], &b_lds[buf][(w * 128 + 64) * 8]);
    };

    f32x4 acc[4][4] = {};
    int nk = K >> 5;
    STAGE(0, 0);
    __syncthreads();          // drains vmcnt(0): buf0 ready
    int cur = 0;
    for (int t = 0; t < nk; ++t) {
        if (t + 1 < nk) STAGE(cur ^ 1, (t + 1) * 32);   // prefetch next tile
        __builtin_amdgcn_sched_barrier(0);              // pin prefetch issue before compute
        bf16x8 afr[4], bfr[4];
        #pragma unroll
        for (int i = 0; i < 4; i++) {
            afr[i] = *(const bf16x8*)&a_lds[cur][(wm + i * 16 + lr) * 32 + lh * 8];
            bfr[i] = *(const bf16x8*)&b_lds[cur][(wn + i * 16 + lr) * 32 + lh * 8];
        }
        #pragma unroll
        for (int i = 0; i < 4; i++)
            #pragma unroll
            for (int j = 0; j < 4; j++)
                acc[i][j] = MFMA16(afr[i], bfr[j], acc[i][j]);
        __syncthreads();      // drains vmcnt(0): next buf ready; all reads of cur done
        cur ^= 1;
    }
    // epilogue
    #pragma unroll
    for (int i = 0; i < 4; i++) {
        #pragma unroll
        for (int j = 0; j < 4; j++) {
            int col = n0 + wn + j * 16 + lr;
            float bv = bias[col];
            #pragma unroll
            for (int r = 0; r < 4; r++) {
                int row = m0 + wm + i * 16 + lh * 4 + r;
                float vv = acc[i][j][r] + bv;
                if (MODE == 2) vv = 0.5f * vv * (1.f + erff(vv * 0.70710678118654752f));
                if (MODE == 1) vv += res[(size_t)row * N + col];
                if (MODE == 1) ((float*)outp)[(size_t)row * N + col] = vv;
                else           ((bf16*)outp)[(size_t)row * N + col] = (bf16)vv;
            }
        }
    }
}

// ---------------- causal flash attention v2 ----------------
// grid: (B*H, S/64) with q-tile reversed (heavy first); 256 threads = 4 waves x 16 q-rows.
// qkv: [B*S][3072] bf16 (q|k|v).  VT: [B*H][64][S] bf16 (pre-transposed V).
__global__ __launch_bounds__(256) void attn_kernel(const bf16* __restrict__ qkv,
                                                   const bf16* __restrict__ VT,
                                                   bf16* __restrict__ ctx) {
    __shared__ __align__(16) bf16 k_lds[64 * 72];
    __shared__ __align__(16) bf16 vt_lds[64 * 72];
    __shared__ __align__(16) bf16 p_lds[4 * 16 * 72];
    int bh = blockIdx.x; int b = bh >> 4, h = bh & 15;
    int qt = gridDim.y - 1 - blockIdx.y;
    int q0 = qt * 64;
    int tid = threadIdx.x, w = tid >> 6, lane = tid & 63;
    int lr = lane & 15, lh = lane >> 4;
    const size_t RS = QKVN;
    const bf16* qbase = qkv + (size_t)b * S_ * RS + h * 64;
    const bf16* kbase = qbase + 1024;
    const bf16* vtb = VT + (size_t)bh * 64 * S_;

    int qrow = q0 + w * 16 + lr;
    bf16x8 aq[2];
    aq[0] = *(const bf16x8*)&qbase[(size_t)qrow * RS + lh * 8];
    aq[1] = *(const bf16x8*)&qbase[(size_t)qrow * RS + 32 + lh * 8];

    f32x4 o_acc[4] = {};
    float mrow[4], lrow[4];
    #pragma unroll
    for (int r = 0; r < 4; r++) { mrow[r] = -1e30f; lrow[r] = 0.f; }

    int er = tid >> 3, ecg = tid & 7;       // staging split: 64 rows x 8 col-granules, 2 iters
    int ntile = qt + 1;
    for (int t = 0; t < ntile; t++) {
        int kv0 = t * 64;
        #pragma unroll
        for (int i = 0; i < 2; i++) {
            int r = er + i * 32;
            *(bf16x8*)&k_lds [r * 72 + ecg * 8] = *(const bf16x8*)&kbase[(size_t)(kv0 + r) * RS + ecg * 8];
            *(bf16x8*)&vt_lds[r * 72 + ecg * 8] = *(const bf16x8*)&vtb  [(size_t)r * S_ + kv0 + ecg * 8];
        }
        __syncthreads();

        // scores: 16 q x 64 kv (4 C-frags), K over d=64 (2 chunks)
        f32x4 sc[4] = {};
        #pragma unroll
        for (int kf = 0; kf < 4; kf++)
            #pragma unroll
            for (int dc = 0; dc < 2; dc++) {
                bf16x8 bk = *(const bf16x8*)&k_lds[(kf * 16 + lr) * 72 + dc * 32 + lh * 8];
                sc[kf] = MFMA16(aq[dc], bk, sc[kf]);
            }

        // scale + causal mask, row max
        float pmax[4];
        #pragma unroll
        for (int r = 0; r < 4; r++) pmax[r] = -1e30f;
        #pragma unroll
        for (int kf = 0; kf < 4; kf++) {
            int kvg = kv0 + kf * 16 + lr;
            #pragma unroll
            for (int r = 0; r < 4; r++) {
                int qg = q0 + w * 16 + lh * 4 + r;
                float sv = sc[kf][r] * 0.125f;
                if (kvg > qg) sv = -100000.0f;
                sc[kf][r] = sv;
                pmax[r] = fmaxf(pmax[r], sv);
            }
        }
        #pragma unroll
        for (int o = 1; o < 16; o <<= 1)
            #pragma unroll
            for (int r = 0; r < 4; r++) pmax[r] = fmaxf(pmax[r], __shfl_xor(pmax[r], o));

        float scl[4], psum[4];
        #pragma unroll
        for (int r = 0; r < 4; r++) {
            float mn = fmaxf(mrow[r], pmax[r]);
            scl[r] = __expf(mrow[r] - mn);
            mrow[r] = mn;
            psum[r] = 0.f;
        }
        #pragma unroll
        for (int kf = 0; kf < 4; kf++)
            #pragma unroll
            for (int r = 0; r < 4; r++) {
                float p = __expf(sc[kf][r] - mrow[r]);
                sc[kf][r] = p;
                psum[r] += p;
            }
        #pragma unroll
        for (int o = 1; o < 16; o <<= 1)
            #pragma unroll
            for (int r = 0; r < 4; r++) psum[r] += __shfl_xor(psum[r], o);
        #pragma unroll
        for (int r = 0; r < 4; r++) lrow[r] = lrow[r] * scl[r] + psum[r];
        #pragma unroll
        for (int j = 0; j < 4; j++)
            #pragma unroll
            for (int r = 0; r < 4; r++) o_acc[j][r] *= scl[r];

        // P (C-layout) -> per-wave LDS -> A-layout fragments
        bf16* pw = &p_lds[w * 16 * 72];
        #pragma unroll
        for (int kf = 0; kf < 4; kf++)
            #pragma unroll
            for (int r = 0; r < 4; r++)
                pw[(lh * 4 + r) * 72 + kf * 16 + lr] = (bf16)sc[kf][r];
        asm volatile("s_waitcnt lgkmcnt(0)" ::: "memory");
        __builtin_amdgcn_sched_barrier(0);
        bf16x8 ap[2];
        ap[0] = *(const bf16x8*)&pw[lr * 72 + lh * 8];
        ap[1] = *(const bf16x8*)&pw[lr * 72 + 32 + lh * 8];
        #pragma unroll
        for (int df = 0; df < 4; df++) {
            #pragma unroll
            for (int kc = 0; kc < 2; kc++) {
                bf16x8 bv = *(const bf16x8*)&vt_lds[(df * 16 + lr) * 72 + kc * 32 + lh * 8];
                o_acc[df] = MFMA16(ap[kc], bv, o_acc[df]);
            }
        }
        __syncthreads();
    }

    #pragma unroll
    for (int df = 0; df < 4; df++)
        #pragma unroll
        for (int r = 0; r < 4; r++) {
            int row = q0 + w * 16 + lh * 4 + r;
            int col = h * 64 + df * 16 + lr;
            ctx[((size_t)b * S_ + row) * D_ + col] = (bf16)(o_acc[df][r] / lrow[r]);
        }
}

extern "C" void kernel_launch(void* const* d_in, const int* in_sizes, int n_in,
                              void* d_out, int out_size, void* d_ws, size_t ws_size,
                              hipStream_t stream) {
    const float* x  = (const float*)d_in[0];
    const float* Wq = (const float*)d_in[1];
    const float* bq = (const float*)d_in[2];
    const float* Wk = (const float*)d_in[3];
    const float* bk = (const float*)d_in[4];
    const float* Wv = (const float*)d_in[5];
    const float* bv = (const float*)d_in[6];
    const float* Wo = (const float*)d_in[7];
    const float* bo = (const float*)d_in[8];
    const float* W1 = (const float*)d_in[9];
    const float* b1 = (const float*)d_in[10];
    const float* W2 = (const float*)d_in[11];
    const float* b2 = (const float*)d_in[12];
    const float* g1 = (const float*)d_in[13];
    const float* s1 = (const float*)d_in[14];
    const float* g2 = (const float*)d_in[15];
    const float* s2 = (const float*)d_in[16];
    float* out = (float*)d_out;

    char* ws = (char*)d_ws;
    size_t off = 0;
    auto alloc = [&](size_t bytes) -> char* {
        char* p = ws + off; off += (bytes + 255) & ~(size_t)255; return p;
    };
    bf16*  wt_qkv = (bf16*)alloc((size_t)QKVN * D_ * 2);
    bf16*  wt_o   = (bf16*)alloc((size_t)D_ * D_ * 2);
    bf16*  wt_1   = (bf16*)alloc((size_t)FF_ * D_ * 2);
    bf16*  wt_2   = (bf16*)alloc((size_t)D_ * FF_ * 2);
    float* qkvb   = (float*)alloc((size_t)QKVN * 4);
    bf16*  h1     = (bf16*)alloc((size_t)M_ * D_ * 2);
    bf16*  qkv    = (bf16*)alloc((size_t)M_ * QKVN * 2);
    bf16*  vtbuf  = (bf16*)alloc((size_t)M_ * D_ * 2);
    bf16*  ctx    = (bf16*)alloc((size_t)M_ * D_ * 2);
    float* x2     = (float*)alloc((size_t)M_ * D_ * 4);
    bf16*  h2     = (bf16*)alloc((size_t)M_ * D_ * 2);
    bf16*  gbuf   = (bf16*)alloc((size_t)M_ * FF_ * 2);

    // weight prep
    transpose_cast<<<dim3(16, 16), 256, 0, stream>>>(Wq, wt_qkv, D_, D_);
    transpose_cast<<<dim3(16, 16), 256, 0, stream>>>(Wk, wt_qkv + (size_t)D_ * D_, D_, D_);
    transpose_cast<<<dim3(16, 16), 256, 0, stream>>>(Wv, wt_qkv + (size_t)2 * D_ * D_, D_, D_);
    transpose_cast<<<dim3(16, 16), 256, 0, stream>>>(Wo, wt_o, D_, D_);
    transpose_cast<<<dim3(16, 64), 256, 0, stream>>>(W1, wt_1, D_, FF_);
    transpose_cast<<<dim3(64, 16), 256, 0, stream>>>(W2, wt_2, FF_, D_);
    concat3<<<12, 256, 0, stream>>>(bq, bk, bv, qkvb);

    // block
    ln_kernel<<<M_ / 4, 256, 0, stream>>>(x, g1, s1, h1);
    gemm_bt<0><<<dim3(QKVN / 128, M_ / 128), 256, 0, stream>>>(h1, wt_qkv, qkvb, nullptr, qkv, M_, QKVN, D_);
    transpose_v<<<dim3(S_ / 64, B_ * H_), 256, 0, stream>>>(qkv, vtbuf);
    attn_kernel<<<dim3(B_ * H_, S_ / 64), 256, 0, stream>>>(qkv, vtbuf, ctx);
    gemm_bt<1><<<dim3(D_ / 128, M_ / 128), 256, 0, stream>>>(ctx, wt_o, bo, x, x2, M_, D_, D_);
    ln_kernel<<<M_ / 4, 256, 0, stream>>>(x2, g2, s2, h2);
    gemm_bt<2><<<dim3(FF_ / 128, M_ / 128), 256, 0, stream>>>(h2, wt_1, b1, nullptr, gbuf, M_, FF_, D_);
    gemm_bt<1><<<dim3(D_ / 128, M_ / 128), 256, 0, stream>>>(gbuf, wt_2, b2, x2, out, M_, D_, FF_);
}

// Round 4
// 397.594 us; speedup vs baseline: 1.5354x; 1.0858x over previous
//
#include <hip/hip_runtime.h>
#include <hip/hip_bf16.h>
#include <math.h>

#define D_   1024
#define H_   16
#define HD_  64
#define S_   2048
#define B_   2
#define FF_  4096
#define M_   (B_*S_)      // 4096 rows
#define QKVN (3*D_)       // 3072

typedef __bf16 bf16;
typedef bf16 bf16x8 __attribute__((ext_vector_type(8)));
typedef bf16 bf16x4 __attribute__((ext_vector_type(4)));
typedef float f32x4 __attribute__((ext_vector_type(4)));

#define MFMA16(a,b,c) __builtin_amdgcn_mfma_f32_16x16x32_bf16(a,b,c,0,0,0)

// async global->LDS 16B per lane (wave-uniform LDS base + lane*16)
__device__ __forceinline__ void gld16(const void* g, void* l) {
    __builtin_amdgcn_global_load_lds(
        (const __attribute__((address_space(1))) void*)g,
        (__attribute__((address_space(3))) void*)l, 16, 0, 0);
}

// ---------------- weight transpose + cast: W[K][N] f32 -> WT[N][K] bf16 ----------------
__global__ __launch_bounds__(256) void transpose_cast(const float* __restrict__ W,
                                                      bf16* __restrict__ WT,
                                                      int K, int N) {
    __shared__ float t[64][65];
    int k0 = blockIdx.x * 64, n0 = blockIdx.y * 64;
    int tid = threadIdx.x;
    #pragma unroll
    for (int i = 0; i < 16; i++) {
        int e = tid + i * 256; int r = e >> 6, c = e & 63;
        t[r][c] = W[(size_t)(k0 + r) * N + n0 + c];
    }
    __syncthreads();
    #pragma unroll
    for (int i = 0; i < 16; i++) {
        int e = tid + i * 256; int r = e >> 6, c = e & 63;
        WT[(size_t)(n0 + r) * K + k0 + c] = (bf16)t[c][r];
    }
}

// ---------------- transpose V section of qkv into VT[bh][d][s] ----------------
__global__ __launch_bounds__(256) void transpose_v(const bf16* __restrict__ qkv,
                                                   bf16* __restrict__ VT) {
    __shared__ __align__(16) bf16 t[64][72];
    int bh = blockIdx.y; int b = bh >> 4, h = bh & 15;
    int s0 = blockIdx.x * 64;
    const bf16* vbase = qkv + (size_t)b * S_ * QKVN + 2048 + h * 64;
    int tid = threadIdx.x;
    #pragma unroll
    for (int i = 0; i < 2; i++) {
        int e = tid + i * 256; int r = e >> 3, cg = e & 7;
        *(bf16x8*)&t[r][cg * 8] = *(const bf16x8*)&vbase[(size_t)(s0 + r) * QKVN + cg * 8];
    }
    __syncthreads();
    #pragma unroll
    for (int i = 0; i < 2; i++) {
        int e = tid + i * 256; int d = e >> 3, cg = e & 7;
        bf16x8 v;
        #pragma unroll
        for (int j = 0; j < 8; j++) v[j] = t[cg * 8 + j][d];
        *(bf16x8*)&VT[((size_t)bh * 64 + d) * S_ + s0 + cg * 8] = v;
    }
}

// ---------------- concat q,k,v biases into one [3072] buffer ----------------
__global__ void concat3(const float* __restrict__ a, const float* __restrict__ b,
                        const float* __restrict__ c, float* __restrict__ o) {
    int i = blockIdx.x * 256 + threadIdx.x;
    o[i] = (i < 1024) ? a[i] : (i < 2048 ? b[i - 1024] : c[i - 2048]);
}

// ---------------- layernorm (ddof=1, eps on std) f32 in -> bf16 out ----------------
__global__ __launch_bounds__(256) void ln_kernel(const float* __restrict__ x,
                                                 const float* __restrict__ g,
                                                 const float* __restrict__ sh,
                                                 bf16* __restrict__ out) {
    int row = blockIdx.x * 4 + (threadIdx.x >> 6);
    int lane = threadIdx.x & 63;
    const float4* xr = (const float4*)(x + (size_t)row * D_);
    float4 v[4]; float sum = 0.f, ss = 0.f;
    #pragma unroll
    for (int c = 0; c < 4; c++) {
        v[c] = xr[lane + 64 * c];
        sum += v[c].x + v[c].y + v[c].z + v[c].w;
        ss  += v[c].x * v[c].x + v[c].y * v[c].y + v[c].z * v[c].z + v[c].w * v[c].w;
    }
    #pragma unroll
    for (int o = 32; o; o >>= 1) { sum += __shfl_xor(sum, o); ss += __shfl_xor(ss, o); }
    float mean = sum * (1.f / 1024.f);
    float var  = (ss - 1024.f * mean * mean) * (1.f / 1023.f);
    float inv  = 1.f / (sqrtf(var) + 1e-5f);
    const float4* gp = (const float4*)g;
    const float4* sp = (const float4*)sh;
    bf16x4* op = (bf16x4*)(out + (size_t)row * D_);
    #pragma unroll
    for (int c = 0; c < 4; c++) {
        int idx = lane + 64 * c;
        float4 gv = gp[idx], sv = sp[idx];
        float y0 = (v[c].x - mean) * inv * gv.x + sv.x;
        float y1 = (v[c].y - mean) * inv * gv.y + sv.y;
        float y2 = (v[c].z - mean) * inv * gv.z + sv.z;
        float y3 = (v[c].w - mean) * inv * gv.w + sv.w;
        op[idx] = (bf16x4){(bf16)y0, (bf16)y1, (bf16)y2, (bf16)y3};
    }
}

// ================= 256x256 BK=32 8-wave triple-buffered counted-vmcnt GEMM =================
// C = A[M,K] @ BT[N,K]^T (+ bias / epilogue).  512 threads = 8 waves (2M x 4N), per-wave 128x64.
// LDS: 3 bufs x (A 256x32 + B 256x32) bf16 = 96 KB. Stage kt+2 while computing kt:
// writes always target buf (kt+2)%3, readers touch kt%3 and (kt+1)%3 -> no WAR/RAW given the
// one end-of-iter s_barrier (all frag ds_reads complete before MFMA via compiler lgkm waits).
// vmcnt(4) per K-step (kt+1's 4 loads landed; kt+2's 4 stay in flight) - never drains to 0.
// XOR swizzle: LDS[row, c] holds global chunk c ^ ((row>>1)&3); read at c = lh ^ ((row>>1)&3)
// -> bank spread = minimal 2-way (free). gld16 dest stays linear (rule #21: swizzle the SOURCE).
// MODE 0: +bias -> bf16.  MODE 2: +bias, exact GELU -> bf16.  MODE 3: raw f32 partial (split-K,
// slice z writes part[z*M*N + row*N + col]).
template<int MODE>
__global__ __launch_bounds__(512, 2) void gemm256(const bf16* __restrict__ A,
                                                  const bf16* __restrict__ BT,
                                                  const float* __restrict__ bias,
                                                  void* __restrict__ outp,
                                                  int M, int N, int K, int KSLICE) {
    __shared__ __align__(16) bf16 a_lds[3 * 256 * 32];
    __shared__ __align__(16) bf16 b_lds[3 * 256 * 32];
    int tid = threadIdx.x, w = tid >> 6, lane = tid & 63;
    // XCD-chunked bijective swizzle over the whole grid (all grids here are %8==0)
    int gx = gridDim.x, gxy = gx * gridDim.y;
    int nwg = gxy * gridDim.z;
    int flat = blockIdx.z * gxy + blockIdx.y * gx + blockIdx.x;
    int chunk = nwg >> 3;
    int swz = (flat & 7) * chunk + (flat >> 3);
    int z = swz / gxy, rem = swz - z * gxy;
    int m0 = (rem / gx) * 256, n0 = (rem % gx) * 256;
    int kbase = z * KSLICE;
    int nk = KSLICE >> 5;
    int lr = lane & 15, lh = lane >> 4;
    int wr = w >> 2, wc = w & 3;

    // staging granules: g = w*64 + lane (+512). row = g>>2, lds chunk = g&3,
    // global chunk = (g&3) ^ ((row>>1)&3). dest base uniform per wave: (g-lane)*8 elems.
    int g0 = w * 64 + lane;
    int row0 = g0 >> 2, cs0 = (g0 & 3) ^ ((row0 >> 1) & 3);
    int g1 = g0 + 512;
    int row1 = g1 >> 2, cs1 = (g1 & 3) ^ ((row1 >> 1) & 3);
    int dst0 = w * 512;
    int dst1 = w * 512 + 4096;

    auto STAGE = [&](int buf, int k0) {
        bf16* ab = a_lds + buf * 8192;
        bf16* bb = b_lds + buf * 8192;
        gld16(&A [(size_t)(m0 + row0) * K + k0 + cs0 * 8], ab + dst0);
        gld16(&A [(size_t)(m0 + row1) * K + k0 + cs1 * 8], ab + dst1);
        gld16(&BT[(size_t)(n0 + row0) * K + k0 + cs0 * 8], bb + dst0);
        gld16(&BT[(size_t)(n0 + row1) * K + k0 + cs1 * 8], bb + dst1);
    };

    f32x4 acc[8][4] = {};
    STAGE(0, kbase);
    STAGE(1, kbase + 32);
    asm volatile("s_waitcnt vmcnt(4)" ::: "memory");   // kt0 landed
    __builtin_amdgcn_s_barrier();
    __builtin_amdgcn_sched_barrier(0);

    int rchk = (lr >> 1) & 3;   // (row>>1)&3 for frag rows (base multiple of 16)
    int fcol = ((lh ^ rchk) * 8);
    for (int kt = 0; kt < nk; ++kt) {
        int b0 = kt % 3;
        const bf16* ab = a_lds + b0 * 8192;
        const bf16* bb = b_lds + b0 * 8192;
        bf16x8 af[8], bf[4];
        #pragma unroll
        for (int m = 0; m < 8; m++)
            af[m] = *(const bf16x8*)&ab[(wr * 128 + m * 16 + lr) * 32 + fcol];
        #pragma unroll
        for (int n = 0; n < 4; n++)
            bf[n] = *(const bf16x8*)&bb[(wc * 64 + n * 16 + lr) * 32 + fcol];
        if (kt + 2 < nk) {
            STAGE((kt + 2) % 3, kbase + (kt + 2) * 32);
            asm volatile("s_waitcnt vmcnt(4)" ::: "memory");   // kt+1 landed, kt+2 in flight
        } else {
            asm volatile("s_waitcnt vmcnt(0)" ::: "memory");   // tail drain
        }
        __builtin_amdgcn_s_setprio(1);
        #pragma unroll
        for (int m = 0; m < 8; m++)
            #pragma unroll
            for (int n = 0; n < 4; n++)
                acc[m][n] = MFMA16(af[m], bf[n], acc[m][n]);
        __builtin_amdgcn_s_setprio(0);
        __builtin_amdgcn_s_barrier();
        __builtin_amdgcn_sched_barrier(0);
    }

    // epilogue
    #pragma unroll
    for (int m = 0; m < 8; m++) {
        #pragma unroll
        for (int n = 0; n < 4; n++) {
            int col = n0 + wc * 64 + n * 16 + lr;
            float bv = (MODE == 3) ? 0.f : bias[col];
            #pragma unroll
            for (int r = 0; r < 4; r++) {
                int row = m0 + wr * 128 + m * 16 + lh * 4 + r;
                float vv = acc[m][n][r] + bv;
                if (MODE == 2) vv = 0.5f * vv * (1.f + erff(vv * 0.70710678118654752f));
                if (MODE == 3) ((float*)outp)[((size_t)z * M + row) * N + col] = vv;
                else           ((bf16*)outp)[(size_t)row * N + col] = (bf16)vv;
            }
        }
    }
}

// ---------------- split-K reduce: out = sum_z part[z] + bias + res (f32, N=1024) ----------------
__global__ __launch_bounds__(256) void reduce4(const float* __restrict__ part,
                                               const float* __restrict__ bias,
                                               const float* __restrict__ res,
                                               float* __restrict__ out) {
    int i = blockIdx.x * 256 + threadIdx.x;          // float4 index over M_*1024
    const float4* p = (const float4*)part;
    const size_t s4 = (size_t)M_ * 1024 / 4;
    float4 a = p[i], b = p[i + s4], c = p[i + 2 * s4], d = p[i + 3 * s4];
    float4 bv = ((const float4*)bias)[i & 255];      // N=1024 -> 256 float4 per row
    float4 rv = ((const float4*)res)[i];
    float4 o;
    o.x = a.x + b.x + c.x + d.x + bv.x + rv.x;
    o.y = a.y + b.y + c.y + d.y + bv.y + rv.y;
    o.z = a.z + b.z + c.z + d.z + bv.z + rv.z;
    o.w = a.w + b.w + c.w + d.w + bv.w + rv.w;
    ((float4*)out)[i] = o;
}

// ---------------- causal flash attention (unchanged from round 2) ----------------
__global__ __launch_bounds__(256) void attn_kernel(const bf16* __restrict__ qkv,
                                                   const bf16* __restrict__ VT,
                                                   bf16* __restrict__ ctx) {
    __shared__ __align__(16) bf16 k_lds[64 * 72];
    __shared__ __align__(16) bf16 vt_lds[64 * 72];
    __shared__ __align__(16) bf16 p_lds[4 * 16 * 72];
    int bh = blockIdx.x; int b = bh >> 4, h = bh & 15;
    int qt = gridDim.y - 1 - blockIdx.y;
    int q0 = qt * 64;
    int tid = threadIdx.x, w = tid >> 6, lane = tid & 63;
    int lr = lane & 15, lh = lane >> 4;
    const size_t RS = QKVN;
    const bf16* qbase = qkv + (size_t)b * S_ * RS + h * 64;
    const bf16* kbase = qbase + 1024;
    const bf16* vtb = VT + (size_t)bh * 64 * S_;

    int qrow = q0 + w * 16 + lr;
    bf16x8 aq[2];
    aq[0] = *(const bf16x8*)&qbase[(size_t)qrow * RS + lh * 8];
    aq[1] = *(const bf16x8*)&qbase[(size_t)qrow * RS + 32 + lh * 8];

    f32x4 o_acc[4] = {};
    float mrow[4], lrow[4];
    #pragma unroll
    for (int r = 0; r < 4; r++) { mrow[r] = -1e30f; lrow[r] = 0.f; }

    int er = tid >> 3, ecg = tid & 7;
    int ntile = qt + 1;
    for (int t = 0; t < ntile; t++) {
        int kv0 = t * 64;
        #pragma unroll
        for (int i = 0; i < 2; i++) {
            int r = er + i * 32;
            *(bf16x8*)&k_lds [r * 72 + ecg * 8] = *(const bf16x8*)&kbase[(size_t)(kv0 + r) * RS + ecg * 8];
            *(bf16x8*)&vt_lds[r * 72 + ecg * 8] = *(const bf16x8*)&vtb  [(size_t)r * S_ + kv0 + ecg * 8];
        }
        __syncthreads();

        f32x4 sc[4] = {};
        #pragma unroll
        for (int kf = 0; kf < 4; kf++)
            #pragma unroll
            for (int dc = 0; dc < 2; dc++) {
                bf16x8 bk = *(const bf16x8*)&k_lds[(kf * 16 + lr) * 72 + dc * 32 + lh * 8];
                sc[kf] = MFMA16(aq[dc], bk, sc[kf]);
            }

        float pmax[4];
        #pragma unroll
        for (int r = 0; r < 4; r++) pmax[r] = -1e30f;
        #pragma unroll
        for (int kf = 0; kf < 4; kf++) {
            int kvg = kv0 + kf * 16 + lr;
            #pragma unroll
            for (int r = 0; r < 4; r++) {
                int qg = q0 + w * 16 + lh * 4 + r;
                float sv = sc[kf][r] * 0.125f;
                if (kvg > qg) sv = -100000.0f;
                sc[kf][r] = sv;
                pmax[r] = fmaxf(pmax[r], sv);
            }
        }
        #pragma unroll
        for (int o = 1; o < 16; o <<= 1)
            #pragma unroll
            for (int r = 0; r < 4; r++) pmax[r] = fmaxf(pmax[r], __shfl_xor(pmax[r], o));

        float scl[4], psum[4];
        #pragma unroll
        for (int r = 0; r < 4; r++) {
            float mn = fmaxf(mrow[r], pmax[r]);
            scl[r] = __expf(mrow[r] - mn);
            mrow[r] = mn;
            psum[r] = 0.f;
        }
        #pragma unroll
        for (int kf = 0; kf < 4; kf++)
            #pragma unroll
            for (int r = 0; r < 4; r++) {
                float p = __expf(sc[kf][r] - mrow[r]);
                sc[kf][r] = p;
                psum[r] += p;
            }
        #pragma unroll
        for (int o = 1; o < 16; o <<= 1)
            #pragma unroll
            for (int r = 0; r < 4; r++) psum[r] += __shfl_xor(psum[r], o);
        #pragma unroll
        for (int r = 0; r < 4; r++) lrow[r] = lrow[r] * scl[r] + psum[r];
        #pragma unroll
        for (int j = 0; j < 4; j++)
            #pragma unroll
            for (int r = 0; r < 4; r++) o_acc[j][r] *= scl[r];

        bf16* pw = &p_lds[w * 16 * 72];
        #pragma unroll
        for (int kf = 0; kf < 4; kf++)
            #pragma unroll
            for (int r = 0; r < 4; r++)
                pw[(lh * 4 + r) * 72 + kf * 16 + lr] = (bf16)sc[kf][r];
        asm volatile("s_waitcnt lgkmcnt(0)" ::: "memory");
        __builtin_amdgcn_sched_barrier(0);
        bf16x8 ap[2];
        ap[0] = *(const bf16x8*)&pw[lr * 72 + lh * 8];
        ap[1] = *(const bf16x8*)&pw[lr * 72 + 32 + lh * 8];
        #pragma unroll
        for (int df = 0; df < 4; df++) {
            #pragma unroll
            for (int kc = 0; kc < 2; kc++) {
                bf16x8 bv = *(const bf16x8*)&vt_lds[(df * 16 + lr) * 72 + kc * 32 + lh * 8];
                o_acc[df] = MFMA16(ap[kc], bv, o_acc[df]);
            }
        }
        __syncthreads();
    }

    #pragma unroll
    for (int df = 0; df < 4; df++)
        #pragma unroll
        for (int r = 0; r < 4; r++) {
            int row = q0 + w * 16 + lh * 4 + r;
            int col = h * 64 + df * 16 + lr;
            ctx[((size_t)b * S_ + row) * D_ + col] = (bf16)(o_acc[df][r] / lrow[r]);
        }
}

extern "C" void kernel_launch(void* const* d_in, const int* in_sizes, int n_in,
                              void* d_out, int out_size, void* d_ws, size_t ws_size,
                              hipStream_t stream) {
    const float* x  = (const float*)d_in[0];
    const float* Wq = (const float*)d_in[1];
    const float* bq = (const float*)d_in[2];
    const float* Wk = (const float*)d_in[3];
    const float* bk = (const float*)d_in[4];
    const float* Wv = (const float*)d_in[5];
    const float* bv = (const float*)d_in[6];
    const float* Wo = (const float*)d_in[7];
    const float* bo = (const float*)d_in[8];
    const float* W1 = (const float*)d_in[9];
    const float* b1 = (const float*)d_in[10];
    const float* W2 = (const float*)d_in[11];
    const float* b2 = (const float*)d_in[12];
    const float* g1 = (const float*)d_in[13];
    const float* s1 = (const float*)d_in[14];
    const float* g2 = (const float*)d_in[15];
    const float* s2 = (const float*)d_in[16];
    float* out = (float*)d_out;

    char* ws = (char*)d_ws;
    size_t off = 0;
    auto alloc = [&](size_t bytes) -> char* {
        char* p = ws + off; off += (bytes + 255) & ~(size_t)255; return p;
    };
    bf16*  wt_qkv = (bf16*)alloc((size_t)QKVN * D_ * 2);
    bf16*  wt_o   = (bf16*)alloc((size_t)D_ * D_ * 2);
    bf16*  wt_1   = (bf16*)alloc((size_t)FF_ * D_ * 2);
    bf16*  wt_2   = (bf16*)alloc((size_t)D_ * FF_ * 2);
    float* qkvb   = (float*)alloc((size_t)QKVN * 4);
    bf16*  h1     = (bf16*)alloc((size_t)M_ * D_ * 2);
    bf16*  qkv    = (bf16*)alloc((size_t)M_ * QKVN * 2);
    bf16*  vtbuf  = (bf16*)alloc((size_t)M_ * D_ * 2);
    bf16*  ctx    = (bf16*)alloc((size_t)M_ * D_ * 2);
    float* x2     = (float*)alloc((size_t)M_ * D_ * 4);
    bf16*  h2     = (bf16*)alloc((size_t)M_ * D_ * 2);
    bf16*  gbuf   = (bf16*)alloc((size_t)M_ * FF_ * 2);
    float* part   = (float*)alloc((size_t)4 * M_ * D_ * 4);   // split-K partials (shared)

    // weight prep
    transpose_cast<<<dim3(16, 16), 256, 0, stream>>>(Wq, wt_qkv, D_, D_);
    transpose_cast<<<dim3(16, 16), 256, 0, stream>>>(Wk, wt_qkv + (size_t)D_ * D_, D_, D_);
    transpose_cast<<<dim3(16, 16), 256, 0, stream>>>(Wv, wt_qkv + (size_t)2 * D_ * D_, D_, D_);
    transpose_cast<<<dim3(16, 16), 256, 0, stream>>>(Wo, wt_o, D_, D_);
    transpose_cast<<<dim3(16, 64), 256, 0, stream>>>(W1, wt_1, D_, FF_);
    transpose_cast<<<dim3(64, 16), 256, 0, stream>>>(W2, wt_2, FF_, D_);
    concat3<<<12, 256, 0, stream>>>(bq, bk, bv, qkvb);

    // block
    ln_kernel<<<M_ / 4, 256, 0, stream>>>(x, g1, s1, h1);
    gemm256<0><<<dim3(QKVN / 256, M_ / 256, 1), 512, 0, stream>>>(h1, wt_qkv, qkvb, qkv, M_, QKVN, D_, D_);
    transpose_v<<<dim3(S_ / 64, B_ * H_), 256, 0, stream>>>(qkv, vtbuf);
    attn_kernel<<<dim3(B_ * H_, S_ / 64), 256, 0, stream>>>(qkv, vtbuf, ctx);
    gemm256<3><<<dim3(D_ / 256, M_ / 256, 4), 512, 0, stream>>>(ctx, wt_o, nullptr, part, M_, D_, D_, D_ / 4);
    reduce4<<<(M_ * D_) / 1024, 256, 0, stream>>>(part, bo, x, x2);
    ln_kernel<<<M_ / 4, 256, 0, stream>>>(x2, g2, s2, h2);
    gemm256<2><<<dim3(FF_ / 256, M_ / 256, 1), 512, 0, stream>>>(h2, wt_1, b1, gbuf, M_, FF_, D_, D_);
    gemm256<3><<<dim3(D_ / 256, M_ / 256, 4), 512, 0, stream>>>(gbuf, wt_2, nullptr, part, M_, D_, FF_, FF_ / 4);
    reduce4<<<(M_ * D_) / 1024, 256, 0, stream>>>(part, b2, x2, out);
}